// Round 6
// baseline (3937.829 us; speedup 1.0000x reference)
//
#include <hip/hip_runtime.h>
#include <math.h>

#define NB 4
#define NPT 1024
#define KNN 20
#define NROW (NB*NPT)

// ---------------- K1: transpose input (B,3,N) -> (B,N,3) ----------------
__global__ __launch_bounds__(256) void k_transpose_in(const float* __restrict__ x,
                                                      float* __restrict__ X1) {
    int t = blockIdx.x*256 + threadIdx.x;            // over B*N*3
    if (t >= NB*NPT*3) return;
    int d = t % 3; int n = (t/3) % NPT; int b = t/(3*NPT);
    X1[t] = x[(b*3 + d)*NPT + n];
}

// ---------------- K2: per-row sum of squares (fp64) ----------------
__global__ __launch_bounds__(256) void k_row_sumsq(const float* __restrict__ X, int S, int F,
                                                   double* __restrict__ xx) {
    int lane = threadIdx.x & 63;
    int row  = blockIdx.x*4 + (threadIdx.x >> 6);
    const float* p = X + (size_t)row * S;
    double s = 0.0;
    for (int f = lane; f < F; f += 64) { double v = (double)p[f]; s += v*v; }
    for (int off = 32; off; off >>= 1) s += __shfl_down(s, off);
    if (lane == 0) xx[row] = s;
}

// ---------------- K3: tiled fp64 distance (shifted: 2*dot - xx_m) ----------------
__global__ __launch_bounds__(256) void k_dist(const float* __restrict__ X, int S, int F,
                                              const double* __restrict__ xx,
                                              double* __restrict__ dist) {
    extern __shared__ double ds[];
    int b = blockIdx.z, n0 = blockIdx.y*16, m0 = blockIdx.x*16;
    const int CH = 192;
    int Fp = (F < CH ? F : CH) + 1;
    double* Xn = ds;
    double* Xm = ds + 16*Fp;
    double acc = 0.0;
    int mi = threadIdx.x & 15, ni = threadIdx.x >> 4;
    for (int f0 = 0; f0 < F; f0 += CH) {
        int fc = F - f0; if (fc > CH) fc = CH;
        __syncthreads();
        for (int t = threadIdx.x; t < 16*fc; t += 256) {
            int r = t / fc, c = t - r*fc;
            Xn[r*Fp + c] = (double)X[((size_t)(b*NPT + n0 + r))*S + f0 + c];
            Xm[r*Fp + c] = (double)X[((size_t)(b*NPT + m0 + r))*S + f0 + c];
        }
        __syncthreads();
        const double* an = Xn + ni*Fp;
        const double* am = Xm + mi*Fp;
        for (int f = 0; f < fc; ++f) acc = fma(an[f], am[f], acc);
    }
    dist[((size_t)(b*NPT + n0 + ni))*NPT + (m0 + mi)] = 2.0*acc - xx[b*NPT + m0 + mi];
}

// ---------------- K4: iterative top-20 (stable, lower index on ties) ----------------
__global__ __launch_bounds__(256) void k_topk(const double* __restrict__ dist,
                                              int* __restrict__ idxo) {
    __shared__ double v[NPT];
    __shared__ double rv[256];
    __shared__ int    ri[256];
    int row = blockIdx.x;                            // b*N+n
    const double* dr = dist + (size_t)row * NPT;
    for (int t = threadIdx.x; t < NPT; t += 256) v[t] = dr[t];
    __syncthreads();
    for (int k = 0; k < KNN; ++k) {
        double bv = -1.0e300; int bi = 0;
        for (int j = threadIdx.x; j < NPT; j += 256) {
            double xv = v[j];
            if (xv > bv) { bv = xv; bi = j; }        // ascending j: keeps lowest idx
        }
        rv[threadIdx.x] = bv; ri[threadIdx.x] = bi;
        __syncthreads();
        for (int s = 128; s; s >>= 1) {
            if (threadIdx.x < s) {
                double ov = rv[threadIdx.x+s]; int oi = ri[threadIdx.x+s];
                if (ov > rv[threadIdx.x] || (ov == rv[threadIdx.x] && oi < ri[threadIdx.x])) {
                    rv[threadIdx.x] = ov; ri[threadIdx.x] = oi;
                }
            }
            __syncthreads();
        }
        if (threadIdx.x == 0) {
            idxo[row*KNN + k] = ri[0];
            v[ri[0]] = -1.0e300;
        }
        __syncthreads();
    }
}

// ---------------- K5: Y/Z precompute.  Y = A@x, Z = (B-A)@x, for Wf and Wd ----------------
template<int CO, int C>
__global__ __launch_bounds__(256) void k_yz(const float* __restrict__ X, int S,
                                            const float* __restrict__ Wf,
                                            const float* __restrict__ Wd,
                                            float* __restrict__ Yf, float* __restrict__ Zf,
                                            float* __restrict__ Yd, float* __restrict__ Zd) {
    extern __shared__ float xl[];                    // [4][C*3]
    constexpr int REP = 256/CO;
    constexpr int PPG = 4/REP;                       // points per thread
    int p0 = blockIdx.x * 4;
    for (int t = threadIdx.x; t < 4*C*3; t += 256) {
        int pt = t / (C*3); int r = t - pt*(C*3);
        xl[t] = X[((size_t)(p0 + pt))*S + r];
    }
    __syncthreads();
    int co  = threadIdx.x % CO;
    int sub = threadIdx.x / CO;
    float yf[PPG][3] = {}, zf[PPG][3] = {}, yd[PPG][3] = {}, zd[PPG][3] = {};
    const float* wfr = Wf + (size_t)co*2*C;
    const float* wdr = Wd + (size_t)co*2*C;
    for (int i = 0; i < C; ++i) {
        float wfa = wfr[i], wfb = wfr[C+i];
        float wda = wdr[i], wdb = wdr[C+i];
        float wfz = wfb - wfa, wdz = wdb - wda;
        #pragma unroll
        for (int q = 0; q < PPG; ++q) {
            int pt = sub*PPG + q;
            const float* xv = xl + pt*(C*3) + i*3;
            #pragma unroll
            for (int d3 = 0; d3 < 3; ++d3) {
                float xe = xv[d3];
                yf[q][d3] = fmaf(wfa, xe, yf[q][d3]);
                zf[q][d3] = fmaf(wfz, xe, zf[q][d3]);
                yd[q][d3] = fmaf(wda, xe, yd[q][d3]);
                zd[q][d3] = fmaf(wdz, xe, zd[q][d3]);
            }
        }
    }
    #pragma unroll
    for (int q = 0; q < PPG; ++q) {
        int pt = sub*PPG + q;
        size_t o = ((size_t)(p0+pt)*CO + co)*3;
        #pragma unroll
        for (int d3 = 0; d3 < 3; ++d3) {
            Yf[o+d3] = yf[q][d3]; Zf[o+d3] = zf[q][d3];
            Yd[o+d3] = yd[q][d3]; Zd[o+d3] = zd[q][d3];
        }
    }
}

// ---------------- K6: pass A — per-channel partial sums of norm, norm^2 ----------------
template<int CO>
__global__ __launch_bounds__(256) void k_passA(const float* __restrict__ Yf,
                                               const float* __restrict__ Zf,
                                               const int* __restrict__ idx,
                                               float* __restrict__ part) {
    constexpr int REP = 256/CO;
    constexpr int PNG = 16/REP;
    int co  = threadIdx.x % CO;
    int sub = threadIdx.x / CO;
    int p0  = blockIdx.x*16 + sub*PNG;
    float s = 0.f, q = 0.f;
    for (int pp = 0; pp < PNG; ++pp) {
        int row = p0 + pp;
        int b   = row >> 10;
        size_t zo = ((size_t)row*CO + co)*3;
        float z0 = Zf[zo], z1 = Zf[zo+1], z2 = Zf[zo+2];
        const int* ir = idx + row*KNN;
        for (int k = 0; k < KNN; ++k) {
            int j = ir[k];
            size_t yo = ((size_t)((b<<10) + j)*CO + co)*3;
            float a0 = Yf[yo] + z0, a1 = Yf[yo+1] + z1, a2 = Yf[yo+2] + z2;
            float nn = sqrtf(a0*a0 + a1*a1 + a2*a2) + 1e-6f;
            s += nn; q += nn*nn;
        }
    }
    size_t o = ((size_t)blockIdx.x*256 + threadIdx.x)*2;
    part[o] = s; part[o+1] = q;
}

// ---------------- K7: stats finalize (fp64) ----------------
__global__ __launch_bounds__(64) void k_stats(const float* __restrict__ part, int nchunk, int CO,
                                              double cnt, float* __restrict__ mu,
                                              float* __restrict__ rstd) {
    int c = blockIdx.x*64 + threadIdx.x;
    if (c >= CO) return;
    double s = 0.0, q = 0.0;
    for (int ch = 0; ch < nchunk; ++ch) {
        size_t o = ((size_t)ch*CO + c)*2;
        s += (double)part[o]; q += (double)part[o+1];
    }
    double m = s/cnt;
    double v = q/cnt - m*m;
    mu[c]   = (float)m;
    rstd[c] = (float)(1.0/sqrt(v + 1e-5));
}

// ---------------- K8: pass B — normalize, flip, mean over k ----------------
template<int CO>
__global__ __launch_bounds__(256) void k_passB(const float* __restrict__ Yf,
                                               const float* __restrict__ Zf,
                                               const float* __restrict__ Yd,
                                               const float* __restrict__ Zd,
                                               const int* __restrict__ idx,
                                               const float* __restrict__ mu,
                                               const float* __restrict__ rstd,
                                               const float* __restrict__ gam,
                                               const float* __restrict__ bet,
                                               float* __restrict__ XC, int choff) {
    constexpr int REP = 256/CO;
    constexpr int PNG = 8/REP;
    int co  = threadIdx.x % CO;
    int sub = threadIdx.x / CO;
    int p0  = blockIdx.x*8 + sub*PNG;
    float m = mu[co], rs = rstd[co], g = gam[co], bt = bet[co];
    for (int pp = 0; pp < PNG; ++pp) {
        int row = p0 + pp;
        int b   = row >> 10;
        size_t zo = ((size_t)row*CO + co)*3;
        float zf0 = Zf[zo], zf1 = Zf[zo+1], zf2 = Zf[zo+2];
        float zd0 = Zd[zo], zd1 = Zd[zo+1], zd2 = Zd[zo+2];
        const int* ir = idx + row*KNN;
        float a0 = 0.f, a1 = 0.f, a2 = 0.f;
        for (int k = 0; k < KNN; ++k) {
            int j = ir[k];
            size_t yo = ((size_t)((b<<10) + j)*CO + co)*3;
            float pv0 = Yf[yo] + zf0, pv1 = Yf[yo+1] + zf1, pv2 = Yf[yo+2] + zf2;
            float d0  = Yd[yo] + zd0, d1  = Yd[yo+1] + zd1, d2  = Yd[yo+2] + zd2;
            float nn  = sqrtf(pv0*pv0 + pv1*pv1 + pv2*pv2) + 1e-6f;
            float nbn = (nn - m)*rs*g + bt;
            float sc  = nbn / nn;
            float q0 = sc*pv0, q1 = sc*pv1, q2 = sc*pv2;
            float dotv = sc*(pv0*d0 + pv1*d1 + pv2*d2);
            if (dotv < 0.f) {
                float dsq = d0*d0 + d1*d1 + d2*d2;
                float cc  = dotv/(dsq + 1e-6f);
                q0 -= cc*d0; q1 -= cc*d1; q2 -= cc*d2;
            }
            a0 += q0; a1 += q1; a2 += q2;
        }
        size_t oo = ((size_t)row*512 + choff + co)*3;
        XC[oo]   = a0*(1.f/KNN);
        XC[oo+1] = a1*(1.f/KNN);
        XC[oo+2] = a2*(1.f/KNN);
    }
}

// ---------------- K9: layer-5 GEMM (P5 = W5f@XC, D5 = W5d@XC) ----------------
__global__ __launch_bounds__(256) void k_gemm5(const float* __restrict__ XC,
                                               const float* __restrict__ W5f,
                                               const float* __restrict__ W5d,
                                               float* __restrict__ P5,
                                               float* __restrict__ D5) {
    extern __shared__ float xl[];                    // 8 * 1536 floats
    int p0 = blockIdx.x * 8;
    for (int t = threadIdx.x; t < 8*1536; t += 256) xl[t] = XC[(size_t)p0*1536 + t];
    __syncthreads();
    int co = blockIdx.y*256 + threadIdx.x;
    float pa[8][3] = {}; float da[8][3] = {};
    const float* wf = W5f + (size_t)co*512;
    const float* wd = W5d + (size_t)co*512;
    for (int i = 0; i < 512; ++i) {
        float a = wf[i], c = wd[i];
        #pragma unroll
        for (int pt = 0; pt < 8; ++pt) {
            const float* xv = xl + pt*1536 + i*3;
            pa[pt][0] = fmaf(a, xv[0], pa[pt][0]);
            pa[pt][1] = fmaf(a, xv[1], pa[pt][1]);
            pa[pt][2] = fmaf(a, xv[2], pa[pt][2]);
            da[pt][0] = fmaf(c, xv[0], da[pt][0]);
            da[pt][1] = fmaf(c, xv[1], da[pt][1]);
            da[pt][2] = fmaf(c, xv[2], da[pt][2]);
        }
    }
    #pragma unroll
    for (int pt = 0; pt < 8; ++pt) {
        size_t o = ((size_t)(p0+pt)*1024 + co)*3;
        #pragma unroll
        for (int d3 = 0; d3 < 3; ++d3) { P5[o+d3] = pa[pt][d3]; D5[o+d3] = da[pt][d3]; }
    }
}

// ---------------- K10: layer-5 pass A ----------------
__global__ __launch_bounds__(256) void k_passA5(const float* __restrict__ P5,
                                                float* __restrict__ part) {
    int p0 = blockIdx.x*16;
    float s[4] = {}, q[4] = {};
    for (int pp = 0; pp < 16; ++pp) {
        size_t base = ((size_t)(p0+pp)*1024)*3;
        #pragma unroll
        for (int qq = 0; qq < 4; ++qq) {
            int co = qq*256 + threadIdx.x;
            size_t o = base + (size_t)co*3;
            float a = P5[o], b = P5[o+1], c = P5[o+2];
            float nn = sqrtf(a*a + b*b + c*c) + 1e-6f;
            s[qq] += nn; q[qq] += nn*nn;
        }
    }
    #pragma unroll
    for (int qq = 0; qq < 4; ++qq) {
        int co = qq*256 + threadIdx.x;
        size_t o = ((size_t)blockIdx.x*1024 + co)*2;
        part[o] = s[qq]; part[o+1] = q[qq];
    }
}

// ---------------- K11: layer-5 pass B (partial mean over n) ----------------
__global__ __launch_bounds__(256) void k_passB5(const float* __restrict__ P5,
                                                const float* __restrict__ D5,
                                                const float* __restrict__ mu,
                                                const float* __restrict__ rstd,
                                                const float* __restrict__ gam,
                                                const float* __restrict__ bet,
                                                float* __restrict__ part) {
    int p0 = blockIdx.x*16;
    float mm[4], rr[4], gg[4], bb[4];
    #pragma unroll
    for (int qq = 0; qq < 4; ++qq) {
        int co = qq*256 + threadIdx.x;
        mm[qq] = mu[co]; rr[qq] = rstd[co]; gg[qq] = gam[co]; bb[qq] = bet[co];
    }
    float acc[4][3] = {};
    for (int pp = 0; pp < 16; ++pp) {
        size_t base = ((size_t)(p0+pp)*1024)*3;
        #pragma unroll
        for (int qq = 0; qq < 4; ++qq) {
            int co = qq*256 + threadIdx.x;
            size_t o = base + (size_t)co*3;
            float a = P5[o], b = P5[o+1], c = P5[o+2];
            float d0 = D5[o], d1 = D5[o+1], d2 = D5[o+2];
            float nn = sqrtf(a*a + b*b + c*c) + 1e-6f;
            float sc = ((nn - mm[qq])*rr[qq]*gg[qq] + bb[qq])/nn;
            float q0 = sc*a, q1 = sc*b, q2 = sc*c;
            float dotv = sc*(a*d0 + b*d1 + c*d2);
            if (dotv < 0.f) {
                float dsq = d0*d0 + d1*d1 + d2*d2;
                float cc  = dotv/(dsq + 1e-6f);
                q0 -= cc*d0; q1 -= cc*d1; q2 -= cc*d2;
            }
            acc[qq][0] += q0; acc[qq][1] += q1; acc[qq][2] += q2;
        }
    }
    #pragma unroll
    for (int qq = 0; qq < 4; ++qq) {
        int co = qq*256 + threadIdx.x;
        size_t o = ((size_t)blockIdx.x*1024 + co)*3;
        part[o] = acc[qq][0]; part[o+1] = acc[qq][1]; part[o+2] = acc[qq][2];
    }
}

// ---------------- K12: final reduce over n-chunks -> d_out ----------------
__global__ __launch_bounds__(256) void k_outred(const float* __restrict__ part,
                                                float* __restrict__ out) {
    int t = blockIdx.x*256 + threadIdx.x;            // over B*1024*3
    if (t >= NB*1024*3) return;
    int d = t % 3; int co = (t/3) % 1024; int b = t/(3*1024);
    float s = 0.f;
    for (int ch = 0; ch < 64; ++ch)
        s += part[((size_t)(b*64 + ch)*1024 + co)*3 + d];
    out[t] = s * (1.f/1024.f);
}

// ---------------- host-side per-layer driver ----------------
template<int CO, int C>
static void run_layer(const float* Xin, int S, const float* Wf, const float* Wd,
                      const float* g, const float* bt, int choff,
                      double* XX, double* DIST, int* IDX,
                      float* Yf, float* Zf, float* Yd, float* Zd,
                      float* PA, float* MU, float* RS, float* XC, hipStream_t stream) {
    constexpr int F = 3*C;
    k_row_sumsq<<<dim3(NROW/4), dim3(256), 0, stream>>>(Xin, S, F, XX);
    size_t dsm = (size_t)2*16*((F < 192 ? F : 192) + 1)*8;
    k_dist<<<dim3(NPT/16, NPT/16, NB), dim3(256), dsm, stream>>>(Xin, S, F, XX, DIST);
    k_topk<<<dim3(NROW), dim3(256), 0, stream>>>(DIST, IDX);
    k_yz<CO, C><<<dim3(NROW/4), dim3(256), (size_t)4*C*3*4, stream>>>(Xin, S, Wf, Wd, Yf, Zf, Yd, Zd);
    k_passA<CO><<<dim3(NROW/16), dim3(256), 0, stream>>>(Yf, Zf, IDX, PA);
    k_stats<<<dim3((CO+63)/64), dim3(64), 0, stream>>>(PA, 256*(256/CO), CO, (double)((size_t)NROW*KNN), MU, RS);
    k_passB<CO><<<dim3(NROW/8), dim3(256), 0, stream>>>(Yf, Zf, Yd, Zd, IDX, MU, RS, g, bt, XC, choff);
}

extern "C" void kernel_launch(void* const* d_in, const int* in_sizes, int n_in,
                              void* d_out, int out_size, void* d_ws, size_t ws_size,
                              hipStream_t stream) {
    const float* x = (const float*)d_in[0];
    const float* Wf[5]; const float* Wd[5]; const float* G[5]; const float* Bt[5];
    for (int l = 0; l < 5; ++l) {
        Wf[l] = (const float*)d_in[1 + 4*l];
        Wd[l] = (const float*)d_in[2 + 4*l];
        G[l]  = (const float*)d_in[3 + 4*l];
        Bt[l] = (const float*)d_in[4 + 4*l];
    }
    float* ws = (float*)d_ws;
    // workspace layout (float slots)
    size_t oXC  = 0;                                 // 4*1024*512*3 = 6291456
    size_t oX1  = oXC  + (size_t)NROW*512*3;
    size_t oXX  = oX1  + (size_t)NROW*3;             // doubles: NROW*2 slots
    size_t oMU  = oXX  + (size_t)NROW*2;
    size_t oRS  = oMU  + 1024;
    size_t oPA  = oRS  + 1024;                       // up to 256*1024*2
    size_t oPB5 = oPA  + (size_t)256*1024*2;
    size_t oIDX = oPB5 + (size_t)256*1024*3;
    size_t oBIG = oIDX + (size_t)NROW*KNN;
    float*  XC  = ws + oXC;
    float*  X1  = ws + oX1;
    double* XX  = (double*)(ws + oXX);
    float*  MU  = ws + oMU;
    float*  RS  = ws + oRS;
    float*  PA  = ws + oPA;
    float*  PB5 = ws + oPB5;
    int*    IDX = (int*)(ws + oIDX);
    // big region: (dist fp64 + Y/Z) overlapped with (P5 + D5)
    double* DIST = (double*)(ws + oBIG);             // 4194304 doubles = 8388608 slots
    float*  Yf = ws + oBIG + 8388608;
    float*  Zf = Yf + 3145728;
    float*  Yd = Zf + 3145728;
    float*  Zd = Yd + 3145728;
    float*  P5 = ws + oBIG;
    float*  D5 = P5 + (size_t)NROW*1024*3;

    (void)in_sizes; (void)n_in; (void)out_size; (void)ws_size;

    k_transpose_in<<<dim3(48), dim3(256), 0, stream>>>(x, X1);

    // layer 1: C=1 (F=3), CO=64, out channels [0,64)
    run_layer<64, 1>(X1, 3, Wf[0], Wd[0], G[0], Bt[0], 0,
                     XX, DIST, IDX, Yf, Zf, Yd, Zd, PA, MU, RS, XC, stream);
    // layer 2: input = XC[:, :, 0:64], CO=64, out [64,128)
    run_layer<64, 64>(XC + 0*3, 512*3, Wf[1], Wd[1], G[1], Bt[1], 64,
                      XX, DIST, IDX, Yf, Zf, Yd, Zd, PA, MU, RS, XC, stream);
    // layer 3: input = XC[:, :, 64:128], CO=128, out [128,256)
    run_layer<128, 64>(XC + 64*3, 512*3, Wf[2], Wd[2], G[2], Bt[2], 128,
                       XX, DIST, IDX, Yf, Zf, Yd, Zd, PA, MU, RS, XC, stream);
    // layer 4: input = XC[:, :, 128:256], CO=256, out [256,512)
    run_layer<256, 128>(XC + 128*3, 512*3, Wf[3], Wd[3], G[3], Bt[3], 256,
                        XX, DIST, IDX, Yf, Zf, Yd, Zd, PA, MU, RS, XC, stream);

    // layer 5
    k_gemm5<<<dim3(NROW/8, 4), dim3(256), (size_t)8*1536*4, stream>>>(XC, Wf[4], Wd[4], P5, D5);
    k_passA5<<<dim3(NROW/16), dim3(256), 0, stream>>>(P5, PA);
    k_stats<<<dim3(16), dim3(64), 0, stream>>>(PA, 256, 1024, (double)NROW, MU, RS);
    k_passB5<<<dim3(NROW/16), dim3(256), 0, stream>>>(P5, D5, MU, RS, G[4], Bt[4], PB5);
    k_outred<<<dim3(48), dim3(256), 0, stream>>>(PB5, (float*)d_out);
}

// Round 10
// 3110.927 us; speedup vs baseline: 1.2658x; 1.2658x over previous
//
#include <hip/hip_runtime.h>
#include <math.h>

#define NB 4
#define NPT 1024
#define KNN 20
#define NROW (NB*NPT)

// ---------------- K1: transpose input (B,3,N) -> (B,N,3) ----------------
__global__ __launch_bounds__(256) void k_transpose_in(const float* __restrict__ x,
                                                      float* __restrict__ X1) {
    int t = blockIdx.x*256 + threadIdx.x;            // over B*N*3
    if (t >= NB*NPT*3) return;
    int d = t % 3; int n = (t/3) % NPT; int b = t/(3*NPT);
    X1[t] = x[(b*3 + d)*NPT + n];
}

// ---------------- K2: per-row sum of squares (fp64) ----------------
__global__ __launch_bounds__(256) void k_row_sumsq(const float* __restrict__ X, int S, int F,
                                                   double* __restrict__ xx) {
    int lane = threadIdx.x & 63;
    int row  = blockIdx.x*4 + (threadIdx.x >> 6);
    const float* p = X + (size_t)row * S;
    double s = 0.0;
    for (int f = lane; f < F; f += 64) { double v = (double)p[f]; s += v*v; }
    for (int off = 32; off; off >>= 1) s += __shfl_down(s, off);
    if (lane == 0) xx[row] = s;
}

// ---------------- K3: tiled distance, fp32 LDS + fp64 accumulate ----------------
// (double)an*(double)am is exact for fp32 inputs regardless of where the cast
// happens, so fp32 staging is bit-identical to fp64 staging; CH=384 makes all
// layers single-chunk (one barrier round).
__global__ __launch_bounds__(256) void k_dist(const float* __restrict__ X, int S, int F,
                                              const double* __restrict__ xx,
                                              double* __restrict__ dist) {
    extern __shared__ float ds[];
    int b = blockIdx.z, n0 = blockIdx.y*16, m0 = blockIdx.x*16;
    const int CH = 384;
    int Fp = (F < CH ? F : CH) + 1;
    float* Xn = ds;
    float* Xm = ds + 16*Fp;
    double acc = 0.0;
    int mi = threadIdx.x & 15, ni = threadIdx.x >> 4;
    for (int f0 = 0; f0 < F; f0 += CH) {
        int fc = F - f0; if (fc > CH) fc = CH;
        __syncthreads();
        for (int t = threadIdx.x; t < 16*fc; t += 256) {
            int r = t / fc, c = t - r*fc;
            Xn[r*Fp + c] = X[((size_t)(b*NPT + n0 + r))*S + f0 + c];
            Xm[r*Fp + c] = X[((size_t)(b*NPT + m0 + r))*S + f0 + c];
        }
        __syncthreads();
        const float* an = Xn + ni*Fp;
        const float* am = Xm + mi*Fp;
        for (int f = 0; f < fc; ++f)
            acc = fma((double)an[f], (double)am[f], acc);
    }
    dist[((size_t)(b*NPT + n0 + ni))*NPT + (m0 + mi)] = 2.0*acc - xx[b*NPT + m0 + mi];
}

// ---------------- K4: iterative top-20 (stable, lower index on ties) ----------------
__global__ __launch_bounds__(256) void k_topk(const double* __restrict__ dist,
                                              int* __restrict__ idxo) {
    __shared__ double v[NPT];
    __shared__ double rv[256];
    __shared__ int    ri[256];
    int row = blockIdx.x;                            // b*N+n
    const double* dr = dist + (size_t)row * NPT;
    for (int t = threadIdx.x; t < NPT; t += 256) v[t] = dr[t];
    __syncthreads();
    for (int k = 0; k < KNN; ++k) {
        double bv = -1.0e300; int bi = 0;
        for (int j = threadIdx.x; j < NPT; j += 256) {
            double xv = v[j];
            if (xv > bv) { bv = xv; bi = j; }        // ascending j: keeps lowest idx
        }
        rv[threadIdx.x] = bv; ri[threadIdx.x] = bi;
        __syncthreads();
        for (int s = 128; s; s >>= 1) {
            if (threadIdx.x < s) {
                double ov = rv[threadIdx.x+s]; int oi = ri[threadIdx.x+s];
                if (ov > rv[threadIdx.x] || (ov == rv[threadIdx.x] && oi < ri[threadIdx.x])) {
                    rv[threadIdx.x] = ov; ri[threadIdx.x] = oi;
                }
            }
            __syncthreads();
        }
        if (threadIdx.x == 0) {
            idxo[row*KNN + k] = ri[0];
            v[ri[0]] = -1.0e300;
        }
        __syncthreads();
    }
}

// ---------------- K5: Y/Z precompute.  Y = A@x, Z = (B-A)@x, for Wf and Wd ----------------
template<int CO, int C>
__global__ __launch_bounds__(256) void k_yz(const float* __restrict__ X, int S,
                                            const float* __restrict__ Wf,
                                            const float* __restrict__ Wd,
                                            float* __restrict__ Yf, float* __restrict__ Zf,
                                            float* __restrict__ Yd, float* __restrict__ Zd) {
    extern __shared__ float xl[];                    // [4][C*3]
    constexpr int REP = 256/CO;
    constexpr int PPG = 4/REP;                       // points per thread
    int p0 = blockIdx.x * 4;
    for (int t = threadIdx.x; t < 4*C*3; t += 256) {
        int pt = t / (C*3); int r = t - pt*(C*3);
        xl[t] = X[((size_t)(p0 + pt))*S + r];
    }
    __syncthreads();
    int co  = threadIdx.x % CO;
    int sub = threadIdx.x / CO;
    float yf[PPG][3] = {}, zf[PPG][3] = {}, yd[PPG][3] = {}, zd[PPG][3] = {};
    const float* wfr = Wf + (size_t)co*2*C;
    const float* wdr = Wd + (size_t)co*2*C;
    for (int i = 0; i < C; ++i) {
        float wfa = wfr[i], wfb = wfr[C+i];
        float wda = wdr[i], wdb = wdr[C+i];
        float wfz = wfb - wfa, wdz = wdb - wda;
        #pragma unroll
        for (int q = 0; q < PPG; ++q) {
            int pt = sub*PPG + q;
            const float* xv = xl + pt*(C*3) + i*3;
            #pragma unroll
            for (int d3 = 0; d3 < 3; ++d3) {
                float xe = xv[d3];
                yf[q][d3] = fmaf(wfa, xe, yf[q][d3]);
                zf[q][d3] = fmaf(wfz, xe, zf[q][d3]);
                yd[q][d3] = fmaf(wda, xe, yd[q][d3]);
                zd[q][d3] = fmaf(wdz, xe, zd[q][d3]);
            }
        }
    }
    #pragma unroll
    for (int q = 0; q < PPG; ++q) {
        int pt = sub*PPG + q;
        size_t o = ((size_t)(p0+pt)*CO + co)*3;
        #pragma unroll
        for (int d3 = 0; d3 < 3; ++d3) {
            Yf[o+d3] = yf[q][d3]; Zf[o+d3] = zf[q][d3];
            Yd[o+d3] = yd[q][d3]; Zd[o+d3] = zd[q][d3];
        }
    }
}

// ---------------- K6: pass A — per-channel partial sums of norm, norm^2 ----------------
template<int CO>
__global__ __launch_bounds__(256) void k_passA(const float* __restrict__ Yf,
                                               const float* __restrict__ Zf,
                                               const int* __restrict__ idx,
                                               float* __restrict__ part) {
    constexpr int REP = 256/CO;
    constexpr int PNG = 16/REP;
    int co  = threadIdx.x % CO;
    int sub = threadIdx.x / CO;
    int p0  = blockIdx.x*16 + sub*PNG;
    float s = 0.f, q = 0.f;
    for (int pp = 0; pp < PNG; ++pp) {
        int row = p0 + pp;
        int b   = row >> 10;
        size_t zo = ((size_t)row*CO + co)*3;
        float z0 = Zf[zo], z1 = Zf[zo+1], z2 = Zf[zo+2];
        const int* ir = idx + row*KNN;
        for (int k = 0; k < KNN; ++k) {
            int j = ir[k];
            size_t yo = ((size_t)((b<<10) + j)*CO + co)*3;
            float a0 = Yf[yo] + z0, a1 = Yf[yo+1] + z1, a2 = Yf[yo+2] + z2;
            float nn = sqrtf(a0*a0 + a1*a1 + a2*a2) + 1e-6f;
            s += nn; q += nn*nn;
        }
    }
    size_t o = ((size_t)blockIdx.x*256 + threadIdx.x)*2;
    part[o] = s; part[o+1] = q;
}

// ---------------- K7: stats finalize (fp64) ----------------
__global__ __launch_bounds__(64) void k_stats(const float* __restrict__ part, int nchunk, int CO,
                                              double cnt, float* __restrict__ mu,
                                              float* __restrict__ rstd) {
    int c = blockIdx.x*64 + threadIdx.x;
    if (c >= CO) return;
    double s = 0.0, q = 0.0;
    for (int ch = 0; ch < nchunk; ++ch) {
        size_t o = ((size_t)ch*CO + c)*2;
        s += (double)part[o]; q += (double)part[o+1];
    }
    double m = s/cnt;
    double v = q/cnt - m*m;
    mu[c]   = (float)m;
    rstd[c] = (float)(1.0/sqrt(v + 1e-5));
}

// ---------------- K8: pass B — normalize, flip, mean over k ----------------
template<int CO>
__global__ __launch_bounds__(256) void k_passB(const float* __restrict__ Yf,
                                               const float* __restrict__ Zf,
                                               const float* __restrict__ Yd,
                                               const float* __restrict__ Zd,
                                               const int* __restrict__ idx,
                                               const float* __restrict__ mu,
                                               const float* __restrict__ rstd,
                                               const float* __restrict__ gam,
                                               const float* __restrict__ bet,
                                               float* __restrict__ XC, int choff) {
    constexpr int REP = 256/CO;
    constexpr int PNG = 8/REP;
    int co  = threadIdx.x % CO;
    int sub = threadIdx.x / CO;
    int p0  = blockIdx.x*8 + sub*PNG;
    float m = mu[co], rs = rstd[co], g = gam[co], bt = bet[co];
    for (int pp = 0; pp < PNG; ++pp) {
        int row = p0 + pp;
        int b   = row >> 10;
        size_t zo = ((size_t)row*CO + co)*3;
        float zf0 = Zf[zo], zf1 = Zf[zo+1], zf2 = Zf[zo+2];
        float zd0 = Zd[zo], zd1 = Zd[zo+1], zd2 = Zd[zo+2];
        const int* ir = idx + row*KNN;
        float a0 = 0.f, a1 = 0.f, a2 = 0.f;
        for (int k = 0; k < KNN; ++k) {
            int j = ir[k];
            size_t yo = ((size_t)((b<<10) + j)*CO + co)*3;
            float pv0 = Yf[yo] + zf0, pv1 = Yf[yo+1] + zf1, pv2 = Yf[yo+2] + zf2;
            float d0  = Yd[yo] + zd0, d1  = Yd[yo+1] + zd1, d2  = Yd[yo+2] + zd2;
            float nn  = sqrtf(pv0*pv0 + pv1*pv1 + pv2*pv2) + 1e-6f;
            float nbn = (nn - m)*rs*g + bt;
            float sc  = nbn / nn;
            float q0 = sc*pv0, q1 = sc*pv1, q2 = sc*pv2;
            float dotv = sc*(pv0*d0 + pv1*d1 + pv2*d2);
            if (dotv < 0.f) {
                float dsq = d0*d0 + d1*d1 + d2*d2;
                float cc  = dotv/(dsq + 1e-6f);
                q0 -= cc*d0; q1 -= cc*d1; q2 -= cc*d2;
            }
            a0 += q0; a1 += q1; a2 += q2;
        }
        size_t oo = ((size_t)row*512 + choff + co)*3;
        XC[oo]   = a0*(1.f/KNN);
        XC[oo+1] = a1*(1.f/KNN);
        XC[oo+2] = a2*(1.f/KNN);
    }
}

// ---------------- K9: layer-5 GEMM, LDS-tiled (P5 = W5f@XC, D5 = W5d@XC) ----------------
// Tile: 64 co x 32 pt per block, K-chunks of 64. Coalesced staging; per-thread
// 4co x 2pt x 3d x 2mat accumulators; VALU-bound (96 FMA-cyc vs ~80 LDS-cyc per k).
// Accumulation order per output is ascending k (identical to previous version).
#define G5_COT 64
#define G5_PTT 32
#define G5_KC  64
__global__ __launch_bounds__(256) void k_gemm5(const float* __restrict__ XC,
                                               const float* __restrict__ W5f,
                                               const float* __restrict__ W5d,
                                               float* __restrict__ P5,
                                               float* __restrict__ D5) {
    __shared__ float Wfs[G5_COT][G5_KC+1];
    __shared__ float Wds[G5_COT][G5_KC+1];
    __shared__ float Xs[G5_PTT][G5_KC*3+1];
    int co0 = blockIdx.x * G5_COT;
    int p0  = blockIdx.y * G5_PTT;
    int tid = threadIdx.x;
    int tco = tid & 15;                              // 16 groups of 4 co
    int tpt = tid >> 4;                              // 16 groups of 2 pt
    float acc_f[4][2][3] = {};
    float acc_d[4][2][3] = {};
    for (int k0 = 0; k0 < 512; k0 += G5_KC) {
        __syncthreads();
        for (int t = tid; t < G5_COT*G5_KC; t += 256) {
            int c = t >> 6, k = t & 63;
            Wfs[c][k] = W5f[(size_t)(co0 + c)*512 + k0 + k];
            Wds[c][k] = W5d[(size_t)(co0 + c)*512 + k0 + k];
        }
        for (int t = tid; t < G5_PTT*G5_KC*3; t += 256) {
            int p = t / (G5_KC*3), r = t - p*(G5_KC*3);
            Xs[p][r] = XC[(size_t)(p0 + p)*1536 + k0*3 + r];
        }
        __syncthreads();
        #pragma unroll 2
        for (int k = 0; k < G5_KC; ++k) {
            float wfv[4], wdv[4];
            #pragma unroll
            for (int j = 0; j < 4; ++j) {
                wfv[j] = Wfs[tco*4+j][k];
                wdv[j] = Wds[tco*4+j][k];
            }
            float xv[2][3];
            #pragma unroll
            for (int q = 0; q < 2; ++q)
                #pragma unroll
                for (int d = 0; d < 3; ++d)
                    xv[q][d] = Xs[tpt*2+q][k*3+d];
            #pragma unroll
            for (int j = 0; j < 4; ++j)
                #pragma unroll
                for (int q = 0; q < 2; ++q)
                    #pragma unroll
                    for (int d = 0; d < 3; ++d) {
                        acc_f[j][q][d] = fmaf(wfv[j], xv[q][d], acc_f[j][q][d]);
                        acc_d[j][q][d] = fmaf(wdv[j], xv[q][d], acc_d[j][q][d]);
                    }
        }
    }
    #pragma unroll
    for (int q = 0; q < 2; ++q) {
        int pt = p0 + tpt*2 + q;
        #pragma unroll
        for (int j = 0; j < 4; ++j) {
            int co = co0 + tco*4 + j;
            size_t o = ((size_t)pt*1024 + co)*3;
            P5[o]   = acc_f[j][q][0];
            P5[o+1] = acc_f[j][q][1];
            P5[o+2] = acc_f[j][q][2];
            D5[o]   = acc_d[j][q][0];
            D5[o+1] = acc_d[j][q][1];
            D5[o+2] = acc_d[j][q][2];
        }
    }
}

// ---------------- K10: layer-5 pass A ----------------
__global__ __launch_bounds__(256) void k_passA5(const float* __restrict__ P5,
                                                float* __restrict__ part) {
    int p0 = blockIdx.x*16;
    float s[4] = {}, q[4] = {};
    for (int pp = 0; pp < 16; ++pp) {
        size_t base = ((size_t)(p0+pp)*1024)*3;
        #pragma unroll
        for (int qq = 0; qq < 4; ++qq) {
            int co = qq*256 + threadIdx.x;
            size_t o = base + (size_t)co*3;
            float a = P5[o], b = P5[o+1], c = P5[o+2];
            float nn = sqrtf(a*a + b*b + c*c) + 1e-6f;
            s[qq] += nn; q[qq] += nn*nn;
        }
    }
    #pragma unroll
    for (int qq = 0; qq < 4; ++qq) {
        int co = qq*256 + threadIdx.x;
        size_t o = ((size_t)blockIdx.x*1024 + co)*2;
        part[o] = s[qq]; part[o+1] = q[qq];
    }
}

// ---------------- K11: layer-5 pass B (partial mean over n) ----------------
__global__ __launch_bounds__(256) void k_passB5(const float* __restrict__ P5,
                                                const float* __restrict__ D5,
                                                const float* __restrict__ mu,
                                                const float* __restrict__ rstd,
                                                const float* __restrict__ gam,
                                                const float* __restrict__ bet,
                                                float* __restrict__ part) {
    int p0 = blockIdx.x*16;
    float mm[4], rr[4], gg[4], bb[4];
    #pragma unroll
    for (int qq = 0; qq < 4; ++qq) {
        int co = qq*256 + threadIdx.x;
        mm[qq] = mu[co]; rr[qq] = rstd[co]; gg[qq] = gam[co]; bb[qq] = bet[co];
    }
    float acc[4][3] = {};
    for (int pp = 0; pp < 16; ++pp) {
        size_t base = ((size_t)(p0+pp)*1024)*3;
        #pragma unroll
        for (int qq = 0; qq < 4; ++qq) {
            int co = qq*256 + threadIdx.x;
            size_t o = base + (size_t)co*3;
            float a = P5[o], b = P5[o+1], c = P5[o+2];
            float d0 = D5[o], d1 = D5[o+1], d2 = D5[o+2];
            float nn = sqrtf(a*a + b*b + c*c) + 1e-6f;
            float sc = ((nn - mm[qq])*rr[qq]*gg[qq] + bb[qq])/nn;
            float q0 = sc*a, q1 = sc*b, q2 = sc*c;
            float dotv = sc*(a*d0 + b*d1 + c*d2);
            if (dotv < 0.f) {
                float dsq = d0*d0 + d1*d1 + d2*d2;
                float cc  = dotv/(dsq + 1e-6f);
                q0 -= cc*d0; q1 -= cc*d1; q2 -= cc*d2;
            }
            acc[qq][0] += q0; acc[qq][1] += q1; acc[qq][2] += q2;
        }
    }
    #pragma unroll
    for (int qq = 0; qq < 4; ++qq) {
        int co = qq*256 + threadIdx.x;
        size_t o = ((size_t)blockIdx.x*1024 + co)*3;
        part[o] = acc[qq][0]; part[o+1] = acc[qq][1]; part[o+2] = acc[qq][2];
    }
}

// ---------------- K12: final reduce over n-chunks -> d_out ----------------
__global__ __launch_bounds__(256) void k_outred(const float* __restrict__ part,
                                                float* __restrict__ out) {
    int t = blockIdx.x*256 + threadIdx.x;            // over B*1024*3
    if (t >= NB*1024*3) return;
    int d = t % 3; int co = (t/3) % 1024; int b = t/(3*1024);
    float s = 0.f;
    for (int ch = 0; ch < 64; ++ch)
        s += part[((size_t)(b*64 + ch)*1024 + co)*3 + d];
    out[t] = s * (1.f/1024.f);
}

// ---------------- host-side per-layer driver ----------------
template<int CO, int C>
static void run_layer(const float* Xin, int S, const float* Wf, const float* Wd,
                      const float* g, const float* bt, int choff,
                      double* XX, double* DIST, int* IDX,
                      float* Yf, float* Zf, float* Yd, float* Zd,
                      float* PA, float* MU, float* RS, float* XC, hipStream_t stream) {
    constexpr int F = 3*C;
    k_row_sumsq<<<dim3(NROW/4), dim3(256), 0, stream>>>(Xin, S, F, XX);
    size_t dsm = (size_t)2*16*((F < 384 ? F : 384) + 1)*4;   // fp32 staging
    k_dist<<<dim3(NPT/16, NPT/16, NB), dim3(256), dsm, stream>>>(Xin, S, F, XX, DIST);
    k_topk<<<dim3(NROW), dim3(256), 0, stream>>>(DIST, IDX);
    k_yz<CO, C><<<dim3(NROW/4), dim3(256), (size_t)4*C*3*4, stream>>>(Xin, S, Wf, Wd, Yf, Zf, Yd, Zd);
    k_passA<CO><<<dim3(NROW/16), dim3(256), 0, stream>>>(Yf, Zf, IDX, PA);
    k_stats<<<dim3((CO+63)/64), dim3(64), 0, stream>>>(PA, 256*(256/CO), CO, (double)((size_t)NROW*KNN), MU, RS);
    k_passB<CO><<<dim3(NROW/8), dim3(256), 0, stream>>>(Yf, Zf, Yd, Zd, IDX, MU, RS, g, bt, XC, choff);
}

extern "C" void kernel_launch(void* const* d_in, const int* in_sizes, int n_in,
                              void* d_out, int out_size, void* d_ws, size_t ws_size,
                              hipStream_t stream) {
    const float* x = (const float*)d_in[0];
    const float* Wf[5]; const float* Wd[5]; const float* G[5]; const float* Bt[5];
    for (int l = 0; l < 5; ++l) {
        Wf[l] = (const float*)d_in[1 + 4*l];
        Wd[l] = (const float*)d_in[2 + 4*l];
        G[l]  = (const float*)d_in[3 + 4*l];
        Bt[l] = (const float*)d_in[4 + 4*l];
    }
    float* ws = (float*)d_ws;
    // workspace layout (float slots)
    size_t oXC  = 0;                                 // 4*1024*512*3 = 6291456
    size_t oX1  = oXC  + (size_t)NROW*512*3;
    size_t oXX  = oX1  + (size_t)NROW*3;             // doubles: NROW*2 slots
    size_t oMU  = oXX  + (size_t)NROW*2;
    size_t oRS  = oMU  + 1024;
    size_t oPA  = oRS  + 1024;                       // up to 256*1024*2
    size_t oPB5 = oPA  + (size_t)256*1024*2;
    size_t oIDX = oPB5 + (size_t)256*1024*3;
    size_t oBIG = oIDX + (size_t)NROW*KNN;
    float*  XC  = ws + oXC;
    float*  X1  = ws + oX1;
    double* XX  = (double*)(ws + oXX);
    float*  MU  = ws + oMU;
    float*  RS  = ws + oRS;
    float*  PA  = ws + oPA;
    float*  PB5 = ws + oPB5;
    int*    IDX = (int*)(ws + oIDX);
    // big region: (dist fp64 + Y/Z) overlapped with (P5 + D5)
    double* DIST = (double*)(ws + oBIG);             // 4194304 doubles = 8388608 slots
    float*  Yf = ws + oBIG + 8388608;
    float*  Zf = Yf + 3145728;
    float*  Yd = Zf + 3145728;
    float*  Zd = Yd + 3145728;
    float*  P5 = ws + oBIG;
    float*  D5 = P5 + (size_t)NROW*1024*3;

    (void)in_sizes; (void)n_in; (void)out_size; (void)ws_size;

    k_transpose_in<<<dim3(48), dim3(256), 0, stream>>>(x, X1);

    // layer 1: C=1 (F=3), CO=64, out channels [0,64)
    run_layer<64, 1>(X1, 3, Wf[0], Wd[0], G[0], Bt[0], 0,
                     XX, DIST, IDX, Yf, Zf, Yd, Zd, PA, MU, RS, XC, stream);
    // layer 2: input = XC[:, :, 0:64], CO=64, out [64,128)
    run_layer<64, 64>(XC + 0*3, 512*3, Wf[1], Wd[1], G[1], Bt[1], 64,
                      XX, DIST, IDX, Yf, Zf, Yd, Zd, PA, MU, RS, XC, stream);
    // layer 3: input = XC[:, :, 64:128], CO=128, out [128,256)
    run_layer<128, 64>(XC + 64*3, 512*3, Wf[2], Wd[2], G[2], Bt[2], 128,
                       XX, DIST, IDX, Yf, Zf, Yd, Zd, PA, MU, RS, XC, stream);
    // layer 4: input = XC[:, :, 128:256], CO=256, out [256,512)
    run_layer<256, 128>(XC + 128*3, 512*3, Wf[3], Wd[3], G[3], Bt[3], 256,
                        XX, DIST, IDX, Yf, Zf, Yd, Zd, PA, MU, RS, XC, stream);

    // layer 5 (tiled GEMM: grid 16 co-tiles x 128 pt-tiles)
    k_gemm5<<<dim3(16, 128), dim3(256), 0, stream>>>(XC, Wf[4], Wd[4], P5, D5);
    k_passA5<<<dim3(NROW/16), dim3(256), 0, stream>>>(P5, PA);
    k_stats<<<dim3(16), dim3(64), 0, stream>>>(PA, 256, 1024, (double)NROW, MU, RS);
    k_passB5<<<dim3(NROW/16), dim3(256), 0, stream>>>(P5, D5, MU, RS, G[4], Bt[4], PB5);
    k_outred<<<dim3(48), dim3(256), 0, stream>>>(PB5, (float*)d_out);
}

// Round 11
// 2681.900 us; speedup vs baseline: 1.4683x; 1.1600x over previous
//
#include <hip/hip_runtime.h>
#include <math.h>

#define NB 4
#define NPT 1024
#define KNN 20
#define NROW (NB*NPT)

// ---------------- K1: transpose input (B,3,N) -> (B,N,3) ----------------
__global__ __launch_bounds__(256) void k_transpose_in(const float* __restrict__ x,
                                                      float* __restrict__ X1) {
    int t = blockIdx.x*256 + threadIdx.x;            // over B*N*3
    if (t >= NB*NPT*3) return;
    int d = t % 3; int n = (t/3) % NPT; int b = t/(3*NPT);
    X1[t] = x[(b*3 + d)*NPT + n];
}

// ---------------- K2: per-row sum of squares (fp64) ----------------
__global__ __launch_bounds__(256) void k_row_sumsq(const float* __restrict__ X, int S, int F,
                                                   double* __restrict__ xx) {
    int lane = threadIdx.x & 63;
    int row  = blockIdx.x*4 + (threadIdx.x >> 6);
    const float* p = X + (size_t)row * S;
    double s = 0.0;
    for (int f = lane; f < F; f += 64) { double v = (double)p[f]; s += v*v; }
    for (int off = 32; off; off >>= 1) s += __shfl_down(s, off);
    if (lane == 0) xx[row] = s;
}

// ---------------- K3: tiled distance, fp32 LDS + fp64 accumulate ----------------
// (double)an*(double)am is exact for fp32 inputs regardless of where the cast
// happens, so fp32 staging is bit-identical to fp64 staging; CH=384 makes all
// layers single-chunk (one barrier round).
__global__ __launch_bounds__(256) void k_dist(const float* __restrict__ X, int S, int F,
                                              const double* __restrict__ xx,
                                              double* __restrict__ dist) {
    extern __shared__ float ds[];
    int b = blockIdx.z, n0 = blockIdx.y*16, m0 = blockIdx.x*16;
    const int CH = 384;
    int Fp = (F < CH ? F : CH) + 1;
    float* Xn = ds;
    float* Xm = ds + 16*Fp;
    double acc = 0.0;
    int mi = threadIdx.x & 15, ni = threadIdx.x >> 4;
    for (int f0 = 0; f0 < F; f0 += CH) {
        int fc = F - f0; if (fc > CH) fc = CH;
        __syncthreads();
        for (int t = threadIdx.x; t < 16*fc; t += 256) {
            int r = t / fc, c = t - r*fc;
            Xn[r*Fp + c] = X[((size_t)(b*NPT + n0 + r))*S + f0 + c];
            Xm[r*Fp + c] = X[((size_t)(b*NPT + m0 + r))*S + f0 + c];
        }
        __syncthreads();
        const float* an = Xn + ni*Fp;
        const float* am = Xm + mi*Fp;
        for (int f = 0; f < fc; ++f)
            acc = fma((double)an[f], (double)am[f], acc);
    }
    dist[((size_t)(b*NPT + n0 + ni))*NPT + (m0 + mi)] = 2.0*acc - xx[b*NPT + m0 + mi];
}

// ---------------- K4: iterative top-20 (stable, lower index on ties) ----------------
__global__ __launch_bounds__(256) void k_topk(const double* __restrict__ dist,
                                              int* __restrict__ idxo) {
    __shared__ double v[NPT];
    __shared__ double rv[256];
    __shared__ int    ri[256];
    int row = blockIdx.x;                            // b*N+n
    const double* dr = dist + (size_t)row * NPT;
    for (int t = threadIdx.x; t < NPT; t += 256) v[t] = dr[t];
    __syncthreads();
    for (int k = 0; k < KNN; ++k) {
        double bv = -1.0e300; int bi = 0;
        for (int j = threadIdx.x; j < NPT; j += 256) {
            double xv = v[j];
            if (xv > bv) { bv = xv; bi = j; }        // ascending j: keeps lowest idx
        }
        rv[threadIdx.x] = bv; ri[threadIdx.x] = bi;
        __syncthreads();
        for (int s = 128; s; s >>= 1) {
            if (threadIdx.x < s) {
                double ov = rv[threadIdx.x+s]; int oi = ri[threadIdx.x+s];
                if (ov > rv[threadIdx.x] || (ov == rv[threadIdx.x] && oi < ri[threadIdx.x])) {
                    rv[threadIdx.x] = ov; ri[threadIdx.x] = oi;
                }
            }
            __syncthreads();
        }
        if (threadIdx.x == 0) {
            idxo[row*KNN + k] = ri[0];
            v[ri[0]] = -1.0e300;
        }
        __syncthreads();
    }
}

// ---------------- K5a: Y/Z precompute, layer-1 only (C=1, W is L1-resident) ----------------
template<int CO, int C>
__global__ __launch_bounds__(256) void k_yz(const float* __restrict__ X, int S,
                                            const float* __restrict__ Wf,
                                            const float* __restrict__ Wd,
                                            float* __restrict__ Yf, float* __restrict__ Zf,
                                            float* __restrict__ Yd, float* __restrict__ Zd) {
    extern __shared__ float xl[];                    // [4][C*3]
    constexpr int REP = 256/CO;
    constexpr int PPG = 4/REP;                       // points per thread
    int p0 = blockIdx.x * 4;
    for (int t = threadIdx.x; t < 4*C*3; t += 256) {
        int pt = t / (C*3); int r = t - pt*(C*3);
        xl[t] = X[((size_t)(p0 + pt))*S + r];
    }
    __syncthreads();
    int co  = threadIdx.x % CO;
    int sub = threadIdx.x / CO;
    float yf[PPG][3] = {}, zf[PPG][3] = {}, yd[PPG][3] = {}, zd[PPG][3] = {};
    const float* wfr = Wf + (size_t)co*2*C;
    const float* wdr = Wd + (size_t)co*2*C;
    for (int i = 0; i < C; ++i) {
        float wfa = wfr[i], wfb = wfr[C+i];
        float wda = wdr[i], wdb = wdr[C+i];
        float wfz = wfb - wfa, wdz = wdb - wda;
        #pragma unroll
        for (int q = 0; q < PPG; ++q) {
            int pt = sub*PPG + q;
            const float* xv = xl + pt*(C*3) + i*3;
            #pragma unroll
            for (int d3 = 0; d3 < 3; ++d3) {
                float xe = xv[d3];
                yf[q][d3] = fmaf(wfa, xe, yf[q][d3]);
                zf[q][d3] = fmaf(wfz, xe, zf[q][d3]);
                yd[q][d3] = fmaf(wda, xe, yd[q][d3]);
                zd[q][d3] = fmaf(wdz, xe, zd[q][d3]);
            }
        }
    }
    #pragma unroll
    for (int q = 0; q < PPG; ++q) {
        int pt = sub*PPG + q;
        size_t o = ((size_t)(p0+pt)*CO + co)*3;
        #pragma unroll
        for (int d3 = 0; d3 < 3; ++d3) {
            Yf[o+d3] = yf[q][d3]; Zf[o+d3] = zf[q][d3];
            Yd[o+d3] = yd[q][d3]; Zd[o+d3] = zd[q][d3];
        }
    }
}

// ---------------- K5b: Y/Z precompute, GEMM-style LDS tiling (layers 2-4) ----------------
// 32co x 32pt tile per block, i-chunks of 32. W staged coalesced into LDS
// (fixes the per-lane row-gather that thrashed L1). Accumulation order over i
// is preserved ascending with one accumulator per output, and wz = wb - wa is
// formed identically -> bitwise identical to k_yz.
template<int CO, int C>
__global__ __launch_bounds__(256) void k_yz2(const float* __restrict__ X, int S,
                                             const float* __restrict__ Wf,
                                             const float* __restrict__ Wd,
                                             float* __restrict__ Yf, float* __restrict__ Zf,
                                             float* __restrict__ Yd, float* __restrict__ Zd) {
    __shared__ float Waf[32][33], Wbf[32][33], Wad[32][33], Wbd[32][33];
    __shared__ float Xs[32][97];                     // 32 pt x 96 (=32i*3) +1 pad
    int co0 = blockIdx.x * 32;
    int p0  = blockIdx.y * 32;
    int tid = threadIdx.x;
    int tco = tid & 15;                              // 16 groups; thread owns co0+tco, co0+tco+16
    int tpt = tid >> 4;                              // 16 groups; thread owns 2 pts
    float yf[2][2][3] = {}, zf[2][2][3] = {}, yd[2][2][3] = {}, zd[2][2][3] = {};
    for (int i0 = 0; i0 < C; i0 += 32) {
        __syncthreads();
        for (int t = tid; t < 1024; t += 256) {
            int c = t >> 5, i = t & 31;
            const float* wfr = Wf + (size_t)(co0 + c)*2*C + i0 + i;
            const float* wdr = Wd + (size_t)(co0 + c)*2*C + i0 + i;
            Waf[c][i] = wfr[0];
            Wbf[c][i] = wfr[C];
            Wad[c][i] = wdr[0];
            Wbd[c][i] = wdr[C];
        }
        for (int t = tid; t < 32*96; t += 256) {
            int p = t / 96, r = t - p*96;
            Xs[p][r] = X[(size_t)(p0 + p)*S + i0*3 + r];
        }
        __syncthreads();
        for (int k = 0; k < 32; ++k) {
            float waf[2], wzf[2], wad[2], wzd[2];
            #pragma unroll
            for (int j = 0; j < 2; ++j) {
                int c = tco + 16*j;
                waf[j] = Waf[c][k];
                wzf[j] = Wbf[c][k] - waf[j];
                wad[j] = Wad[c][k];
                wzd[j] = Wbd[c][k] - wad[j];
            }
            float xv[2][3];
            #pragma unroll
            for (int q = 0; q < 2; ++q)
                #pragma unroll
                for (int d = 0; d < 3; ++d)
                    xv[q][d] = Xs[tpt*2+q][k*3+d];
            #pragma unroll
            for (int j = 0; j < 2; ++j)
                #pragma unroll
                for (int q = 0; q < 2; ++q)
                    #pragma unroll
                    for (int d = 0; d < 3; ++d) {
                        float xe = xv[q][d];
                        yf[j][q][d] = fmaf(waf[j], xe, yf[j][q][d]);
                        zf[j][q][d] = fmaf(wzf[j], xe, zf[j][q][d]);
                        yd[j][q][d] = fmaf(wad[j], xe, yd[j][q][d]);
                        zd[j][q][d] = fmaf(wzd[j], xe, zd[j][q][d]);
                    }
        }
    }
    #pragma unroll
    for (int q = 0; q < 2; ++q) {
        int pt = p0 + tpt*2 + q;
        #pragma unroll
        for (int j = 0; j < 2; ++j) {
            int co = co0 + tco + 16*j;
            size_t o = ((size_t)pt*CO + co)*3;
            #pragma unroll
            for (int d = 0; d < 3; ++d) {
                Yf[o+d] = yf[j][q][d];
                Zf[o+d] = zf[j][q][d];
                Yd[o+d] = yd[j][q][d];
                Zd[o+d] = zd[j][q][d];
            }
        }
    }
}

// ---------------- K6: pass A — per-channel partial sums of norm, norm^2 ----------------
template<int CO>
__global__ __launch_bounds__(256) void k_passA(const float* __restrict__ Yf,
                                               const float* __restrict__ Zf,
                                               const int* __restrict__ idx,
                                               float* __restrict__ part) {
    constexpr int REP = 256/CO;
    constexpr int PNG = 16/REP;
    int co  = threadIdx.x % CO;
    int sub = threadIdx.x / CO;
    int p0  = blockIdx.x*16 + sub*PNG;
    float s = 0.f, q = 0.f;
    for (int pp = 0; pp < PNG; ++pp) {
        int row = p0 + pp;
        int b   = row >> 10;
        size_t zo = ((size_t)row*CO + co)*3;
        float z0 = Zf[zo], z1 = Zf[zo+1], z2 = Zf[zo+2];
        const int* ir = idx + row*KNN;
        for (int k = 0; k < KNN; ++k) {
            int j = ir[k];
            size_t yo = ((size_t)((b<<10) + j)*CO + co)*3;
            float a0 = Yf[yo] + z0, a1 = Yf[yo+1] + z1, a2 = Yf[yo+2] + z2;
            float nn = sqrtf(a0*a0 + a1*a1 + a2*a2) + 1e-6f;
            s += nn; q += nn*nn;
        }
    }
    size_t o = ((size_t)blockIdx.x*256 + threadIdx.x)*2;
    part[o] = s; part[o+1] = q;
}

// ---------------- K7: stats finalize (fp64) ----------------
__global__ __launch_bounds__(64) void k_stats(const float* __restrict__ part, int nchunk, int CO,
                                              double cnt, float* __restrict__ mu,
                                              float* __restrict__ rstd) {
    int c = blockIdx.x*64 + threadIdx.x;
    if (c >= CO) return;
    double s = 0.0, q = 0.0;
    for (int ch = 0; ch < nchunk; ++ch) {
        size_t o = ((size_t)ch*CO + c)*2;
        s += (double)part[o]; q += (double)part[o+1];
    }
    double m = s/cnt;
    double v = q/cnt - m*m;
    mu[c]   = (float)m;
    rstd[c] = (float)(1.0/sqrt(v + 1e-5));
}

// ---------------- K8: pass B — normalize, flip, mean over k ----------------
template<int CO>
__global__ __launch_bounds__(256) void k_passB(const float* __restrict__ Yf,
                                               const float* __restrict__ Zf,
                                               const float* __restrict__ Yd,
                                               const float* __restrict__ Zd,
                                               const int* __restrict__ idx,
                                               const float* __restrict__ mu,
                                               const float* __restrict__ rstd,
                                               const float* __restrict__ gam,
                                               const float* __restrict__ bet,
                                               float* __restrict__ XC, int choff) {
    constexpr int REP = 256/CO;
    constexpr int PNG = 8/REP;
    int co  = threadIdx.x % CO;
    int sub = threadIdx.x / CO;
    int p0  = blockIdx.x*8 + sub*PNG;
    float m = mu[co], rs = rstd[co], g = gam[co], bt = bet[co];
    for (int pp = 0; pp < PNG; ++pp) {
        int row = p0 + pp;
        int b   = row >> 10;
        size_t zo = ((size_t)row*CO + co)*3;
        float zf0 = Zf[zo], zf1 = Zf[zo+1], zf2 = Zf[zo+2];
        float zd0 = Zd[zo], zd1 = Zd[zo+1], zd2 = Zd[zo+2];
        const int* ir = idx + row*KNN;
        float a0 = 0.f, a1 = 0.f, a2 = 0.f;
        for (int k = 0; k < KNN; ++k) {
            int j = ir[k];
            size_t yo = ((size_t)((b<<10) + j)*CO + co)*3;
            float pv0 = Yf[yo] + zf0, pv1 = Yf[yo+1] + zf1, pv2 = Yf[yo+2] + zf2;
            float d0  = Yd[yo] + zd0, d1  = Yd[yo+1] + zd1, d2  = Yd[yo+2] + zd2;
            float nn  = sqrtf(pv0*pv0 + pv1*pv1 + pv2*pv2) + 1e-6f;
            float nbn = (nn - m)*rs*g + bt;
            float sc  = nbn / nn;
            float q0 = sc*pv0, q1 = sc*pv1, q2 = sc*pv2;
            float dotv = sc*(pv0*d0 + pv1*d1 + pv2*d2);
            if (dotv < 0.f) {
                float dsq = d0*d0 + d1*d1 + d2*d2;
                float cc  = dotv/(dsq + 1e-6f);
                q0 -= cc*d0; q1 -= cc*d1; q2 -= cc*d2;
            }
            a0 += q0; a1 += q1; a2 += q2;
        }
        size_t oo = ((size_t)row*512 + choff + co)*3;
        XC[oo]   = a0*(1.f/KNN);
        XC[oo+1] = a1*(1.f/KNN);
        XC[oo+2] = a2*(1.f/KNN);
    }
}

// ---------------- K9: layer-5 GEMM, LDS-tiled (P5 = W5f@XC, D5 = W5d@XC) ----------------
#define G5_COT 64
#define G5_PTT 32
#define G5_KC  64
__global__ __launch_bounds__(256) void k_gemm5(const float* __restrict__ XC,
                                               const float* __restrict__ W5f,
                                               const float* __restrict__ W5d,
                                               float* __restrict__ P5,
                                               float* __restrict__ D5) {
    __shared__ float Wfs[G5_COT][G5_KC+1];
    __shared__ float Wds[G5_COT][G5_KC+1];
    __shared__ float Xs[G5_PTT][G5_KC*3+1];
    int co0 = blockIdx.x * G5_COT;
    int p0  = blockIdx.y * G5_PTT;
    int tid = threadIdx.x;
    int tco = tid & 15;                              // 16 groups of 4 co
    int tpt = tid >> 4;                              // 16 groups of 2 pt
    float acc_f[4][2][3] = {};
    float acc_d[4][2][3] = {};
    for (int k0 = 0; k0 < 512; k0 += G5_KC) {
        __syncthreads();
        for (int t = tid; t < G5_COT*G5_KC; t += 256) {
            int c = t >> 6, k = t & 63;
            Wfs[c][k] = W5f[(size_t)(co0 + c)*512 + k0 + k];
            Wds[c][k] = W5d[(size_t)(co0 + c)*512 + k0 + k];
        }
        for (int t = tid; t < G5_PTT*G5_KC*3; t += 256) {
            int p = t / (G5_KC*3), r = t - p*(G5_KC*3);
            Xs[p][r] = XC[(size_t)(p0 + p)*1536 + k0*3 + r];
        }
        __syncthreads();
        #pragma unroll 2
        for (int k = 0; k < G5_KC; ++k) {
            float wfv[4], wdv[4];
            #pragma unroll
            for (int j = 0; j < 4; ++j) {
                wfv[j] = Wfs[tco*4+j][k];
                wdv[j] = Wds[tco*4+j][k];
            }
            float xv[2][3];
            #pragma unroll
            for (int q = 0; q < 2; ++q)
                #pragma unroll
                for (int d = 0; d < 3; ++d)
                    xv[q][d] = Xs[tpt*2+q][k*3+d];
            #pragma unroll
            for (int j = 0; j < 4; ++j)
                #pragma unroll
                for (int q = 0; q < 2; ++q)
                    #pragma unroll
                    for (int d = 0; d < 3; ++d) {
                        acc_f[j][q][d] = fmaf(wfv[j], xv[q][d], acc_f[j][q][d]);
                        acc_d[j][q][d] = fmaf(wdv[j], xv[q][d], acc_d[j][q][d]);
                    }
        }
    }
    #pragma unroll
    for (int q = 0; q < 2; ++q) {
        int pt = p0 + tpt*2 + q;
        #pragma unroll
        for (int j = 0; j < 4; ++j) {
            int co = co0 + tco*4 + j;
            size_t o = ((size_t)pt*1024 + co)*3;
            P5[o]   = acc_f[j][q][0];
            P5[o+1] = acc_f[j][q][1];
            P5[o+2] = acc_f[j][q][2];
            D5[o]   = acc_d[j][q][0];
            D5[o+1] = acc_d[j][q][1];
            D5[o+2] = acc_d[j][q][2];
        }
    }
}

// ---------------- K10: layer-5 pass A ----------------
__global__ __launch_bounds__(256) void k_passA5(const float* __restrict__ P5,
                                                float* __restrict__ part) {
    int p0 = blockIdx.x*16;
    float s[4] = {}, q[4] = {};
    for (int pp = 0; pp < 16; ++pp) {
        size_t base = ((size_t)(p0+pp)*1024)*3;
        #pragma unroll
        for (int qq = 0; qq < 4; ++qq) {
            int co = qq*256 + threadIdx.x;
            size_t o = base + (size_t)co*3;
            float a = P5[o], b = P5[o+1], c = P5[o+2];
            float nn = sqrtf(a*a + b*b + c*c) + 1e-6f;
            s[qq] += nn; q[qq] += nn*nn;
        }
    }
    #pragma unroll
    for (int qq = 0; qq < 4; ++qq) {
        int co = qq*256 + threadIdx.x;
        size_t o = ((size_t)blockIdx.x*1024 + co)*2;
        part[o] = s[qq]; part[o+1] = q[qq];
    }
}

// ---------------- K11: layer-5 pass B (partial mean over n) ----------------
__global__ __launch_bounds__(256) void k_passB5(const float* __restrict__ P5,
                                                const float* __restrict__ D5,
                                                const float* __restrict__ mu,
                                                const float* __restrict__ rstd,
                                                const float* __restrict__ gam,
                                                const float* __restrict__ bet,
                                                float* __restrict__ part) {
    int p0 = blockIdx.x*16;
    float mm[4], rr[4], gg[4], bb[4];
    #pragma unroll
    for (int qq = 0; qq < 4; ++qq) {
        int co = qq*256 + threadIdx.x;
        mm[qq] = mu[co]; rr[qq] = rstd[co]; gg[qq] = gam[co]; bb[qq] = bet[co];
    }
    float acc[4][3] = {};
    for (int pp = 0; pp < 16; ++pp) {
        size_t base = ((size_t)(p0+pp)*1024)*3;
        #pragma unroll
        for (int qq = 0; qq < 4; ++qq) {
            int co = qq*256 + threadIdx.x;
            size_t o = base + (size_t)co*3;
            float a = P5[o], b = P5[o+1], c = P5[o+2];
            float d0 = D5[o], d1 = D5[o+1], d2 = D5[o+2];
            float nn = sqrtf(a*a + b*b + c*c) + 1e-6f;
            float sc = ((nn - mm[qq])*rr[qq]*gg[qq] + bb[qq])/nn;
            float q0 = sc*a, q1 = sc*b, q2 = sc*c;
            float dotv = sc*(a*d0 + b*d1 + c*d2);
            if (dotv < 0.f) {
                float dsq = d0*d0 + d1*d1 + d2*d2;
                float cc  = dotv/(dsq + 1e-6f);
                q0 -= cc*d0; q1 -= cc*d1; q2 -= cc*d2;
            }
            acc[qq][0] += q0; acc[qq][1] += q1; acc[qq][2] += q2;
        }
    }
    #pragma unroll
    for (int qq = 0; qq < 4; ++qq) {
        int co = qq*256 + threadIdx.x;
        size_t o = ((size_t)blockIdx.x*1024 + co)*3;
        part[o] = acc[qq][0]; part[o+1] = acc[qq][1]; part[o+2] = acc[qq][2];
    }
}

// ---------------- K12: final reduce over n-chunks -> d_out ----------------
__global__ __launch_bounds__(256) void k_outred(const float* __restrict__ part,
                                                float* __restrict__ out) {
    int t = blockIdx.x*256 + threadIdx.x;            // over B*1024*3
    if (t >= NB*1024*3) return;
    int d = t % 3; int co = (t/3) % 1024; int b = t/(3*1024);
    float s = 0.f;
    for (int ch = 0; ch < 64; ++ch)
        s += part[((size_t)(b*64 + ch)*1024 + co)*3 + d];
    out[t] = s * (1.f/1024.f);
}

// ---------------- host-side per-layer driver ----------------
template<int CO, int C>
static void run_layer(const float* Xin, int S, const float* Wf, const float* Wd,
                      const float* g, const float* bt, int choff,
                      double* XX, double* DIST, int* IDX,
                      float* Yf, float* Zf, float* Yd, float* Zd,
                      float* PA, float* MU, float* RS, float* XC, hipStream_t stream) {
    constexpr int F = 3*C;
    k_row_sumsq<<<dim3(NROW/4), dim3(256), 0, stream>>>(Xin, S, F, XX);
    size_t dsm = (size_t)2*16*((F < 384 ? F : 384) + 1)*4;   // fp32 staging
    k_dist<<<dim3(NPT/16, NPT/16, NB), dim3(256), dsm, stream>>>(Xin, S, F, XX, DIST);
    k_topk<<<dim3(NROW), dim3(256), 0, stream>>>(DIST, IDX);
    if constexpr (C >= 32) {
        k_yz2<CO, C><<<dim3(CO/32, NROW/32), dim3(256), 0, stream>>>(Xin, S, Wf, Wd, Yf, Zf, Yd, Zd);
    } else {
        k_yz<CO, C><<<dim3(NROW/4), dim3(256), (size_t)4*C*3*4, stream>>>(Xin, S, Wf, Wd, Yf, Zf, Yd, Zd);
    }
    k_passA<CO><<<dim3(NROW/16), dim3(256), 0, stream>>>(Yf, Zf, IDX, PA);
    k_stats<<<dim3((CO+63)/64), dim3(64), 0, stream>>>(PA, 256*(256/CO), CO, (double)((size_t)NROW*KNN), MU, RS);
    k_passB<CO><<<dim3(NROW/8), dim3(256), 0, stream>>>(Yf, Zf, Yd, Zd, IDX, MU, RS, g, bt, XC, choff);
}

extern "C" void kernel_launch(void* const* d_in, const int* in_sizes, int n_in,
                              void* d_out, int out_size, void* d_ws, size_t ws_size,
                              hipStream_t stream) {
    const float* x = (const float*)d_in[0];
    const float* Wf[5]; const float* Wd[5]; const float* G[5]; const float* Bt[5];
    for (int l = 0; l < 5; ++l) {
        Wf[l] = (const float*)d_in[1 + 4*l];
        Wd[l] = (const float*)d_in[2 + 4*l];
        G[l]  = (const float*)d_in[3 + 4*l];
        Bt[l] = (const float*)d_in[4 + 4*l];
    }
    float* ws = (float*)d_ws;
    // workspace layout (float slots)
    size_t oXC  = 0;                                 // 4*1024*512*3 = 6291456
    size_t oX1  = oXC  + (size_t)NROW*512*3;
    size_t oXX  = oX1  + (size_t)NROW*3;             // doubles: NROW*2 slots
    size_t oMU  = oXX  + (size_t)NROW*2;
    size_t oRS  = oMU  + 1024;
    size_t oPA  = oRS  + 1024;                       // up to 256*1024*2
    size_t oPB5 = oPA  + (size_t)256*1024*2;
    size_t oIDX = oPB5 + (size_t)256*1024*3;
    size_t oBIG = oIDX + (size_t)NROW*KNN;
    float*  XC  = ws + oXC;
    float*  X1  = ws + oX1;
    double* XX  = (double*)(ws + oXX);
    float*  MU  = ws + oMU;
    float*  RS  = ws + oRS;
    float*  PA  = ws + oPA;
    float*  PB5 = ws + oPB5;
    int*    IDX = (int*)(ws + oIDX);
    // big region: (dist fp64 + Y/Z) overlapped with (P5 + D5)
    double* DIST = (double*)(ws + oBIG);             // 4194304 doubles = 8388608 slots
    float*  Yf = ws + oBIG + 8388608;
    float*  Zf = Yf + 3145728;
    float*  Yd = Zf + 3145728;
    float*  Zd = Yd + 3145728;
    float*  P5 = ws + oBIG;
    float*  D5 = P5 + (size_t)NROW*1024*3;

    (void)in_sizes; (void)n_in; (void)out_size; (void)ws_size;

    k_transpose_in<<<dim3(48), dim3(256), 0, stream>>>(x, X1);

    // layer 1: C=1 (F=3), CO=64, out channels [0,64)
    run_layer<64, 1>(X1, 3, Wf[0], Wd[0], G[0], Bt[0], 0,
                     XX, DIST, IDX, Yf, Zf, Yd, Zd, PA, MU, RS, XC, stream);
    // layer 2: input = XC[:, :, 0:64], CO=64, out [64,128)
    run_layer<64, 64>(XC + 0*3, 512*3, Wf[1], Wd[1], G[1], Bt[1], 64,
                      XX, DIST, IDX, Yf, Zf, Yd, Zd, PA, MU, RS, XC, stream);
    // layer 3: input = XC[:, :, 64:128], CO=128, out [128,256)
    run_layer<128, 64>(XC + 64*3, 512*3, Wf[2], Wd[2], G[2], Bt[2], 128,
                       XX, DIST, IDX, Yf, Zf, Yd, Zd, PA, MU, RS, XC, stream);
    // layer 4: input = XC[:, :, 128:256], CO=256, out [256,512)
    run_layer<256, 128>(XC + 128*3, 512*3, Wf[3], Wd[3], G[3], Bt[3], 256,
                        XX, DIST, IDX, Yf, Zf, Yd, Zd, PA, MU, RS, XC, stream);

    // layer 5 (tiled GEMM: grid 16 co-tiles x 128 pt-tiles)
    k_gemm5<<<dim3(16, 128), dim3(256), 0, stream>>>(XC, Wf[4], Wd[4], P5, D5);
    k_passA5<<<dim3(NROW/16), dim3(256), 0, stream>>>(P5, PA);
    k_stats<<<dim3(16), dim3(64), 0, stream>>>(PA, 256, 1024, (double)NROW, MU, RS);
    k_passB5<<<dim3(NROW/16), dim3(256), 0, stream>>>(P5, D5, MU, RS, G[4], Bt[4], PB5);
    k_outred<<<dim3(48), dim3(256), 0, stream>>>(PB5, (float*)d_out);
}